// Round 10
// baseline (310.999 us; speedup 1.0000x reference)
//
#include <hip/hip_runtime.h>

typedef unsigned short ushort_t;
typedef short short8 __attribute__((ext_vector_type(8)));
typedef float float4v __attribute__((ext_vector_type(4)));

__device__ __forceinline__ float bf2f(ushort_t u) {
    union { unsigned int i; float f; } x; x.i = ((unsigned int)u) << 16; return x.f;
}
__device__ __forceinline__ ushort_t f2bf(float f) {
    unsigned int u = __float_as_uint(f);
    unsigned int r = (u + 0x7FFFu + ((u >> 16) & 1u)) >> 16;
    return (ushort_t)r;
}
__device__ __forceinline__ void store_out(float* p, float v) { *p = v; }
__device__ __forceinline__ void store_out(ushort_t* p, float v) { *p = f2bf(v); }

// async global->LDS 16B/lane; lds ptr must be wave-uniform base (lane*16 auto)
__device__ __forceinline__ void gll16(const ushort_t* g, ushort_t* l) {
    __builtin_amdgcn_global_load_lds(
        (const __attribute__((address_space(1))) void*)g,
        (__attribute__((address_space(3))) void*)l, 16, 0, 0);
}

// ---------------------------------------------------------------------------
// Input-dtype detection. flag=1 -> inputs bf16; flag=0 -> inputs f32.
// ---------------------------------------------------------------------------
__global__ void detect_dtype(const ushort_t* __restrict__ tgt, int* __restrict__ flag) {
    __shared__ int red[256];
    const int tid = threadIdx.x;
    int p = 0;
    for (int i = tid; i < 512; i += 256) {
        ushort_t u = tgt[i];
        int e = (u >> 7) & 0xFF;
        if (u == 0 || (e >= 100 && e <= 140)) ++p;
    }
    red[tid] = p; __syncthreads();
    for (int off = 128; off > 0; off >>= 1) {
        if (tid < off) red[tid] += red[tid + off];
        __syncthreads();
    }
    if (tid == 0) flag[0] = (red[0] >= 480) ? 1 : 0;
}

// ---------------------------------------------------------------------------
// Unified prep (grid 32x32x13):
//   z 0..9 : weight transpose src[K][N] -> dst[N][K] bf16 via 64x64 LDS tile
//   z 10/11: tgt/mem -> bf16 (1024 blocks x 256 thr x 8 elems = 2M)
//   z 12   : biases -> packed f32 [6656] (first 26 linear blocks)
// ---------------------------------------------------------------------------
__global__ __launch_bounds__(256) void prep_all(
    const void* sWq, const void* sWk, const void* sWv, const void* sWo,
    const void* cWq, const void* cWk, const void* cWv, const void* cWo,
    const void* fW1, const void* fW2,
    const void* tgt, const void* mem,
    const void* sbq, const void* sbk, const void* sbv, const void* sbo,
    const void* cbq, const void* cbk, const void* cbv, const void* cbo,
    const void* fb1, const void* fb2,
    ushort_t* __restrict__ wb, ushort_t* __restrict__ tb, ushort_t* __restrict__ mb,
    float* __restrict__ pb, const int* __restrict__ dflag)
{
    const bool f32 = (dflag[0] == 0);
    const int tid = threadIdx.x;
    const int z = blockIdx.z;

    if (z < 10) {
        const void* src; ushort_t* dst; int Kd, Nd;
        switch (z) {
            case 0: src = sWq; dst = wb + 0;       Kd = 512;  Nd = 512;  break;
            case 1: src = sWk; dst = wb + 262144;  Kd = 512;  Nd = 512;  break;
            case 2: src = sWv; dst = wb + 524288;  Kd = 512;  Nd = 512;  break;
            case 3: src = sWo; dst = wb + 786432;  Kd = 512;  Nd = 512;  break;
            case 4: src = cWq; dst = wb + 1048576; Kd = 512;  Nd = 512;  break;
            case 5: src = cWk; dst = wb + 1310720; Kd = 512;  Nd = 512;  break;
            case 6: src = cWv; dst = wb + 1572864; Kd = 512;  Nd = 512;  break;
            case 7: src = cWo; dst = wb + 1835008; Kd = 512;  Nd = 512;  break;
            case 8: src = fW1; dst = wb + 2097152; Kd = 512;  Nd = 2048; break;
            default:src = fW2; dst = wb + 3145728; Kd = 2048; Nd = 512;  break;
        }
        const int k0 = blockIdx.x * 64, n0 = blockIdx.y * 64;
        if (k0 >= Kd || n0 >= Nd) return;
        __shared__ ushort_t T[64][65];
#pragma unroll
        for (int i = 0; i < 16; ++i) {
            int j = i * 256 + tid;
            int r = j >> 6, c = j & 63;
            float v = f32 ? ((const float*)src)[(size_t)(k0 + r) * Nd + n0 + c]
                          : bf2f(((const ushort_t*)src)[(size_t)(k0 + r) * Nd + n0 + c]);
            T[r][c] = f2bf(v);
        }
        __syncthreads();
#pragma unroll
        for (int i = 0; i < 16; ++i) {
            int j = i * 256 + tid;
            int n = j >> 6, k = j & 63;
            dst[(size_t)(n0 + n) * Kd + k0 + k] = T[k][n];
        }
        return;
    }

    const int bid = blockIdx.x * 32 + blockIdx.y;
    if (z < 12) {
        const void* src = (z == 10) ? tgt : mem;
        ushort_t* dst = (z == 10) ? tb : mb;
        const int i = (bid * 256 + tid) * 8;
        if (f32) {
            float4 v0 = *(const float4*)((const float*)src + i);
            float4 v1 = *(const float4*)((const float*)src + i + 4);
            ushort_t o[8] = { f2bf(v0.x), f2bf(v0.y), f2bf(v0.z), f2bf(v0.w),
                              f2bf(v1.x), f2bf(v1.y), f2bf(v1.z), f2bf(v1.w) };
            *(uint4*)(dst + i) = *(const uint4*)o;
        } else {
            *(uint4*)(dst + i) = *(const uint4*)((const ushort_t*)src + i);
        }
        return;
    }

    {   // z == 12: biases
        const int i = bid * 256 + tid;
        if (bid >= 26 || i >= 6656) return;
        const void* src; int off;
        if      (i < 512)  { src = sbq; off = i; }
        else if (i < 1024) { src = sbk; off = i - 512; }
        else if (i < 1536) { src = sbv; off = i - 1024; }
        else if (i < 2048) { src = sbo; off = i - 1536; }
        else if (i < 2560) { src = cbq; off = i - 2048; }
        else if (i < 3072) { src = cbk; off = i - 2560; }
        else if (i < 3584) { src = cbv; off = i - 3072; }
        else if (i < 4096) { src = cbo; off = i - 3584; }
        else if (i < 6144) { src = fb1; off = i - 4096; }
        else               { src = fb2; off = i - 6144; }
        pb[i] = f32 ? ((const float*)src)[off] : bf2f(((const ushort_t*)src)[off]);
    }
}

// ---------------------------------------------------------------------------
// GEMM: C[M][N] = act(A[M][K] @ Wt[N][K]^T + bias). BM=128, BN in {128,64},
// BK=32, DOUBLE-BUFFERED LDS with a single barrier at loop top: iter k
// prefetches tile k+1 via global_load_lds right after the barrier, computes
// tile k's 16 MFMAs, and only the NEXT iteration's barrier (vmcnt(0) drain)
// waits on the prefetch — the load has the whole MFMA phase to land, vs the
// old 2-barrier shape where latency was fully exposed. LDS 2x(BM+BN)x32x2B
// stays <=32KB so occupancy is unchanged (avoids the 64KB cliff).
// Conflict-free additive swizzle: LDS (row r, chunk cc) holds global k-chunk
// (cc - (r>>1))&3; frag reads then hit 8 bank-groups x 2 lanes = free, and
// staging is a within-64B permutation (fully coalesced).
// Dual-A via ySplit merges the cross-attn Q/KV projections into one dispatch.
// ---------------------------------------------------------------------------
template<typename OutT, bool RELU, int BN>
__global__ __launch_bounds__(256) void gemm_tn(
    const ushort_t* __restrict__ A1, const ushort_t* __restrict__ A2,
    int ySplit, int lda,
    const ushort_t* __restrict__ Wt, int ldw,
    const float* __restrict__ bias,
    OutT* __restrict__ C, int ldc, int K)
{
    constexpr int MI = (BN == 128) ? 4 : 2;   // 16-row m-tiles per wave
    __shared__ ushort_t As[2][128][32];
    __shared__ ushort_t Bs[2][BN][32];
    const int tid = threadIdx.x;
    const int wave = tid >> 6, lane = tid & 63;
    const int quad = lane >> 4, l16 = lane & 15;
    const int m0 = blockIdx.x * 128, n0 = blockIdx.y * BN;
    const int wm = (BN == 128) ? (wave >> 1) * 64 : wave * 32;
    const int wn = (BN == 128) ? (wave & 1) * 64 : 0;
    const ushort_t* A = (((int)blockIdx.y) < ySplit) ? A1 : A2;

    float4v acc[MI][4];
#pragma unroll
    for (int mi = 0; mi < MI; ++mi)
#pragma unroll
        for (int ni = 0; ni < 4; ++ni) {
            acc[mi][ni][0] = 0.f; acc[mi][ni][1] = 0.f;
            acc[mi][ni][2] = 0.f; acc[mi][ni][3] = 0.f;
        }

    // staging: lane -> (row srow within 16-row slab, stored chunk scc);
    // source global chunk sg so that stored (r,cc) holds chunk (cc-(r>>1))&3.
    const int srow = lane >> 2;
    const int scc  = lane & 3;
    const int sg   = (scc - (lane >> 3)) & 3;
    const ushort_t* aptr0 = A  + (size_t)(m0 + wave * 16 + srow) * lda + sg * 8;
    const ushort_t* aptr1 = A  + (size_t)(m0 + 64 + wave * 16 + srow) * lda + sg * 8;
    const ushort_t* bptr0 = Wt + (size_t)(n0 + wave * 16 + srow) * ldw + sg * 8;
    const ushort_t* bptr1 = Wt + (size_t)(n0 + 64 + wave * 16 + srow) * ldw + sg * 8;

    // prologue: stage tile 0 into buffer 0
    gll16(aptr0, &As[0][wave * 16][0]);
    gll16(aptr1, &As[0][64 + wave * 16][0]);
    gll16(bptr0, &Bs[0][wave * 16][0]);
    if (BN == 128) gll16(bptr1, &Bs[0][64 + wave * 16][0]);

    const int ca = ((quad + (l16 >> 1)) & 3) * 8;   // swizzled frag column
    int cur = 0;
    for (int k0 = 0; k0 < K; k0 += 32) {
        __syncthreads();   // drains tile-k loads (issued a full MFMA phase ago)
        if (k0 + 32 < K) {
            const int nb = cur ^ 1, ko = k0 + 32;
            gll16(aptr0 + ko, &As[nb][wave * 16][0]);
            gll16(aptr1 + ko, &As[nb][64 + wave * 16][0]);
            gll16(bptr0 + ko, &Bs[nb][wave * 16][0]);
            if (BN == 128) gll16(bptr1 + ko, &Bs[nb][64 + wave * 16][0]);
        }
        short8 af[MI], bfr[4];
#pragma unroll
        for (int mi = 0; mi < MI; ++mi)
            af[mi] = *(const short8*)(&As[cur][wm + mi * 16 + l16][ca]);
#pragma unroll
        for (int ni = 0; ni < 4; ++ni)
            bfr[ni] = *(const short8*)(&Bs[cur][wn + ni * 16 + l16][ca]);
#pragma unroll
        for (int mi = 0; mi < MI; ++mi)
#pragma unroll
            for (int ni = 0; ni < 4; ++ni)
                acc[mi][ni] = __builtin_amdgcn_mfma_f32_16x16x32_bf16(
                    af[mi], bfr[ni], acc[mi][ni], 0, 0, 0);
        cur ^= 1;
    }

#pragma unroll
    for (int ni = 0; ni < 4; ++ni) {
        const int col = n0 + wn + ni * 16 + l16;
        const float bv = bias[col];
#pragma unroll
        for (int mi = 0; mi < MI; ++mi)
#pragma unroll
            for (int r = 0; r < 4; ++r) {
                const int row = m0 + wm + mi * 16 + quad * 4 + r;
                float v = acc[mi][ni][r] + bv;
                if (RELU) v = fmaxf(v, 0.f);
                store_out(&C[(size_t)row * ldc + col], v);
            }
    }
}

// ---------------------------------------------------------------------------
// Flash attention (MFMA) over packed qkv [4096][1536]. Fixed-reference
// streaming softmax (exact for O/l). V staged transposed via s-pair packed
// u32 LDS writes. O written in-place over Q (block-disjoint tiles).
// Unchanged from round 9 (passed).
// ---------------------------------------------------------------------------
__global__ __launch_bounds__(256) void attn_mfma(ushort_t* __restrict__ QKV)
{
    const int S = 1536;
    __shared__ ushort_t Qs[64][72];
    __shared__ ushort_t Ks[64][72];
    __shared__ ushort_t Vt[64][72];
    __shared__ ushort_t Ps[4][16][72];

    const int tid  = threadIdx.x;
    const int wave = tid >> 6, lane = tid & 63;
    const int quad = lane >> 4, l16 = lane & 15;
    const int qt = blockIdx.x, bh = blockIdx.y;
    const int b = bh >> 3, h = bh & 7;
    const size_t rowQ = (size_t)b * 1024 + qt * 64;
    const size_t kv0  = (size_t)b * 1024;

    {
        const int r = tid >> 2, c = (tid & 3) * 16;
        const ushort_t* src = QKV + (rowQ + r) * S + h * 64 + c;
        *(uint4*)(&Qs[r][c])     = *(const uint4*)(src);
        *(uint4*)(&Qs[r][c + 8]) = *(const uint4*)(src + 8);
    }
    __syncthreads();
    short8 qf[2];
    qf[0] = *(const short8*)(&Qs[wave * 16 + l16][quad * 8]);
    qf[1] = *(const short8*)(&Qs[wave * 16 + l16][32 + quad * 8]);

    const float CEXP = 0.125f * 1.44269504f;   // head-scale * log2(e)
    const float MREF = 16.0f * CEXP;           // fixed softmax reference
    float lsum[4];
    float4v oacc[4];
#pragma unroll
    for (int r = 0; r < 4; ++r) lsum[r] = 0.f;
#pragma unroll
    for (int n = 0; n < 4; ++n) { oacc[n][0]=0.f; oacc[n][1]=0.f; oacc[n][2]=0.f; oacc[n][3]=0.f; }

    for (int s0 = 0; s0 < 1024; s0 += 64) {
        __syncthreads();
        {   // K tile, direct
            const int r = tid >> 2, c = (tid & 3) * 16;
            const ushort_t* ksrc = QKV + (kv0 + s0 + r) * S + 512 + h * 64 + c;
            *(uint4*)(&Ks[r][c])     = *(const uint4*)(ksrc);
            *(uint4*)(&Ks[r][c + 8]) = *(const uint4*)(ksrc + 8);
        }
        {   // V tile, transposed: one s-pair x 8 d per thread, packed u32
            const int sp = tid >> 3, dc = (tid & 7) * 8;
            const int r0 = sp * 2;
            const ushort_t* v0 = QKV + (kv0 + s0 + r0) * S + 1024 + h * 64 + dc;
            uint4 a = *(const uint4*)v0;
            uint4 bq = *(const uint4*)(v0 + S);
            const ushort_t* ae = (const ushort_t*)&a;
            const ushort_t* be = (const ushort_t*)&bq;
            const int rg = r0 >> 3, rof = r0 & 7;
#pragma unroll
            for (int j = 0; j < 8; ++j) {
                const int d = dc + j;
                const int cc = (rg ^ (d >> 4)) & 7;
                *(unsigned int*)(&Vt[d][cc * 8 + rof]) =
                    (unsigned int)ae[j] | ((unsigned int)be[j] << 16);
            }
        }
        __syncthreads();

        // QK^T
        float4v sc[4];
#pragma unroll
        for (int sb = 0; sb < 4; ++sb) {
            float4v z; z[0]=0.f; z[1]=0.f; z[2]=0.f; z[3]=0.f;
            short8 kf0 = *(const short8*)(&Ks[sb * 16 + l16][quad * 8]);
            short8 kf1 = *(const short8*)(&Ks[sb * 16 + l16][32 + quad * 8]);
            z = __builtin_amdgcn_mfma_f32_16x16x32_bf16(qf[0], kf0, z, 0, 0, 0);
            z = __builtin_amdgcn_mfma_f32_16x16x32_bf16(qf[1], kf1, z, 0, 0, 0);
            sc[sb] = z;
        }

        // streaming softmax, fixed reference
#pragma unroll
        for (int sb = 0; sb < 4; ++sb)
#pragma unroll
            for (int r = 0; r < 4; ++r) {
                float p = exp2f(fmaf(sc[sb][r], CEXP, -MREF));
                lsum[r] += p;
                Ps[wave][quad * 4 + r][sb * 16 + l16] = f2bf(p);
            }

        // PV
        short8 pf[2];
        pf[0] = *(const short8*)(&Ps[wave][l16][quad * 8]);
        pf[1] = *(const short8*)(&Ps[wave][l16][32 + quad * 8]);
#pragma unroll
        for (int n = 0; n < 4; ++n) {
#pragma unroll
            for (int kc = 0; kc < 2; ++kc) {
                const int cc = ((kc * 4 + quad) ^ n) & 7;
                short8 vf = *(const short8*)(&Vt[n * 16 + l16][cc * 8]);
                oacc[n] = __builtin_amdgcn_mfma_f32_16x16x32_bf16(pf[kc], vf, oacc[n], 0, 0, 0);
            }
        }
    }

    // single final l reduction across the 16 s-lanes of each quad-group
#pragma unroll
    for (int msk = 1; msk < 16; msk <<= 1)
#pragma unroll
        for (int r = 0; r < 4; ++r) lsum[r] += __shfl_xor(lsum[r], msk);
    float inv[4];
#pragma unroll
    for (int r = 0; r < 4; ++r) inv[r] = 1.f / lsum[r];
#pragma unroll
    for (int n = 0; n < 4; ++n)
#pragma unroll
        for (int r = 0; r < 4; ++r) {
            const size_t row = rowQ + wave * 16 + quad * 4 + r;
            QKV[row * S + h * 64 + n * 16 + l16] = f2bf(oacc[n][r] * inv[r]);
        }
}

// ---------------------------------------------------------------------------
// LayerNorm over E=512, wave-shuffle reductions (2 barriers).
// ---------------------------------------------------------------------------
template<bool RES_EXT, bool DELTA_F32, bool OUT_FLAG>
__global__ __launch_bounds__(256) void ln_kernel(
    const void* __restrict__ res, const void* __restrict__ delta,
    const void* __restrict__ g, const void* __restrict__ be,
    void* __restrict__ out, const int* __restrict__ dflag)
{
    const int E = 512;
    const bool extf32 = (dflag[0] == 0);
    const int row = blockIdx.x, tid = threadIdx.x;
    const int wave = tid >> 6, lane = tid & 63;
    const size_t base = (size_t)row * E;
    const int i0 = tid, i1 = tid + 256;

    float r0, r1;
    if (RES_EXT && extf32) {
        r0 = ((const float*)res)[base + i0];
        r1 = ((const float*)res)[base + i1];
    } else {
        r0 = bf2f(((const ushort_t*)res)[base + i0]);
        r1 = bf2f(((const ushort_t*)res)[base + i1]);
    }
    float d0v, d1v;
    if (DELTA_F32) {
        d0v = ((const float*)delta)[base + i0];
        d1v = ((const float*)delta)[base + i1];
    } else {
        d0v = bf2f(((const ushort_t*)delta)[base + i0]);
        d1v = bf2f(((const ushort_t*)delta)[base + i1]);
    }
    float x0 = r0 + d0v, x1 = r1 + d1v;

    __shared__ float red8[8];
    float s = x0 + x1;
#pragma unroll
    for (int m = 1; m < 64; m <<= 1) s += __shfl_xor(s, m);
    if (lane == 0) red8[wave] = s;
    __syncthreads();
    float mean = (red8[0] + red8[1] + red8[2] + red8[3]) * (1.0f / 512.0f);
    float dd0 = x0 - mean, dd1 = x1 - mean;
    float v = dd0 * dd0 + dd1 * dd1;
#pragma unroll
    for (int m = 1; m < 64; m <<= 1) v += __shfl_xor(v, m);
    if (lane == 0) red8[4 + wave] = v;
    __syncthreads();
    float rstd = rsqrtf((red8[4] + red8[5] + red8[6] + red8[7]) * (1.0f / 512.0f) + 1e-5f);

    float g0, g1v, b0, b1;
    if (extf32) {
        g0 = ((const float*)g)[i0];  g1v = ((const float*)g)[i1];
        b0 = ((const float*)be)[i0]; b1  = ((const float*)be)[i1];
    } else {
        g0 = bf2f(((const ushort_t*)g)[i0]);  g1v = bf2f(((const ushort_t*)g)[i1]);
        b0 = bf2f(((const ushort_t*)be)[i0]); b1  = bf2f(((const ushort_t*)be)[i1]);
    }
    float y0 = dd0 * rstd * g0 + b0;
    float y1 = dd1 * rstd * g1v + b1;
    if (OUT_FLAG && extf32) {
        ((float*)out)[base + i0] = y0; ((float*)out)[base + i1] = y1;
    } else {
        ((ushort_t*)out)[base + i0] = f2bf(y0);
        ((ushort_t*)out)[base + i1] = f2bf(y1);
    }
}

// ---------------------------------------------------------------------------
// Workspace (~36.3 MiB):
//   [ 0 ..12M) qkv bf16 [4096][1536]   } FFN phase: hb bf16 [4096][2048]
//   [12M..16M) po  bf16 [4096][512]    }   occupies [0..16M)
//   [16M..20M) xb  bf16 [4096][512]  (residual, live through FFN)
//   [20M..24M) tb  bf16 (tgt)   } FFN phase: of f32 [4096][512] at [20..28M)
//   [24M..28M) mb  bf16 (mem)   }
//   [28M..36M) wb  bf16 transposed weights
//   [36M..]    pb  f32 packed biases; dflag at +256K
// ---------------------------------------------------------------------------

extern "C" void kernel_launch(void* const* d_in, const int* in_sizes, int n_in,
                              void* d_out, int out_size, void* d_ws, size_t ws_size,
                              hipStream_t stream) {
    const void* tgt = d_in[0];
    const void* mem = d_in[1];
    const void* sWq = d_in[2];  const void* sWk = d_in[3];
    const void* sWv = d_in[4];  const void* sWo = d_in[5];
    const void* cWq = d_in[6];  const void* cWk = d_in[7];
    const void* cWv = d_in[8];  const void* cWo = d_in[9];
    const void* sbq = d_in[10]; const void* sbk = d_in[11];
    const void* sbv = d_in[12]; const void* sbo = d_in[13];
    const void* cbq = d_in[14]; const void* cbk = d_in[15];
    const void* cbv = d_in[16]; const void* cbo = d_in[17];
    const void* fW1 = d_in[18]; const void* fb1 = d_in[19];
    const void* fW2 = d_in[20]; const void* fb2 = d_in[21];
    const void* g1  = d_in[22]; const void* g2  = d_in[23];
    const void* g3  = d_in[24];
    const void* be1 = d_in[25]; const void* be2 = d_in[26];
    const void* be3 = d_in[27];

    char* ws = (char*)d_ws;
    const size_t MB = 1048576;
    ushort_t* qkv = (ushort_t*)(ws + 0 * MB);
    ushort_t* hb  = (ushort_t*)(ws + 0 * MB);    // FFN hidden [4096][2048]
    ushort_t* po  = (ushort_t*)(ws + 12 * MB);
    ushort_t* xb  = (ushort_t*)(ws + 16 * MB);
    ushort_t* tb  = (ushort_t*)(ws + 20 * MB);
    ushort_t* mb  = (ushort_t*)(ws + 24 * MB);
    float*    of  = (float*)   (ws + 20 * MB);   // FFN out f32 [4096][512]
    ushort_t* wb  = (ushort_t*)(ws + 28 * MB);
    float*    pb  = (float*)   (ws + 36 * MB);
    int*   dflag  = (int*)     (ws + 36 * MB + 262144);

    const ushort_t* sWqkv_t = wb + 0;
    const ushort_t* sWo_t   = wb + 786432;
    const ushort_t* cWqkv_t = wb + 1048576;   // cWq_t|cWk_t|cWv_t contiguous
    const ushort_t* cWo_t   = wb + 1835008;
    const ushort_t* fW1_t   = wb + 2097152;
    const ushort_t* fW2_t   = wb + 3145728;

    dim3 blk(256);

    // ---- prep ----
    detect_dtype<<<dim3(1), blk, 0, stream>>>((const ushort_t*)tgt, dflag);
    prep_all<<<dim3(32, 32, 13), blk, 0, stream>>>(
        sWq, sWk, sWv, sWo, cWq, cWk, cWv, cWo, fW1, fW2,
        tgt, mem, sbq, sbk, sbv, sbo, cbq, cbk, cbv, cbo, fb1, fb2,
        wb, tb, mb, pb, dflag);

    dim3 gattn(16, 32);

    // ---- self-attention ----
    gemm_tn<ushort_t, false, 128><<<dim3(32, 12), blk, 0, stream>>>(tb, tb, 0, 512, sWqkv_t, 512, pb + 0, qkv, 1536, 512);
    attn_mfma<<<gattn, blk, 0, stream>>>(qkv);
    gemm_tn<ushort_t, false, 64><<<dim3(32, 8), blk, 0, stream>>>(qkv, qkv, 0, 1536, sWo_t, 512, pb + 1536, po, 512, 512);
    ln_kernel<true, false, false><<<dim3(4096), blk, 0, stream>>>(tgt, po, g1, be1, xb, dflag);

    // ---- cross-attention (Q-proj and KV-proj fused into one dispatch) ----
    gemm_tn<ushort_t, false, 128><<<dim3(32, 12), blk, 0, stream>>>(xb, mb, 4, 512, cWqkv_t, 512, pb + 2048, qkv, 1536, 512);
    attn_mfma<<<gattn, blk, 0, stream>>>(qkv);
    gemm_tn<ushort_t, false, 64><<<dim3(32, 8), blk, 0, stream>>>(qkv, qkv, 0, 1536, cWo_t, 512, pb + 3584, po, 512, 512);
    ln_kernel<false, false, false><<<dim3(4096), blk, 0, stream>>>(xb, po, g2, be2, xb, dflag);

    // ---- FFN: full-width, single pass each ----
    gemm_tn<ushort_t, true, 128><<<dim3(32, 16), blk, 0, stream>>>(xb, xb, 0, 512, fW1_t, 512, pb + 4096, hb, 2048, 512);
    gemm_tn<float, false, 64><<<dim3(32, 8), blk, 0, stream>>>(hb, hb, 0, 2048, fW2_t, 2048, pb + 6144, of, 512, 2048);
    ln_kernel<false, true, true><<<dim3(4096), blk, 0, stream>>>(xb, of, g3, be3, d_out, dflag);
}

// Round 11
// 305.519 us; speedup vs baseline: 1.0179x; 1.0179x over previous
//
#include <hip/hip_runtime.h>

typedef unsigned short ushort_t;
typedef short short8 __attribute__((ext_vector_type(8)));
typedef float float4v __attribute__((ext_vector_type(4)));

__device__ __forceinline__ float bf2f(ushort_t u) {
    union { unsigned int i; float f; } x; x.i = ((unsigned int)u) << 16; return x.f;
}
__device__ __forceinline__ ushort_t f2bf(float f) {
    unsigned int u = __float_as_uint(f);
    unsigned int r = (u + 0x7FFFu + ((u >> 16) & 1u)) >> 16;
    return (ushort_t)r;
}
__device__ __forceinline__ void store_out(float* p, float v) { *p = v; }
__device__ __forceinline__ void store_out(ushort_t* p, float v) { *p = f2bf(v); }

// async global->LDS 16B/lane; lds ptr must be wave-uniform base (lane*16 auto)
__device__ __forceinline__ void gll16(const ushort_t* g, ushort_t* l) {
    __builtin_amdgcn_global_load_lds(
        (const __attribute__((address_space(1))) void*)g,
        (__attribute__((address_space(3))) void*)l, 16, 0, 0);
}

// ---------------------------------------------------------------------------
// Input-dtype detection. flag=1 -> inputs bf16; flag=0 -> inputs f32.
// ---------------------------------------------------------------------------
__global__ void detect_dtype(const ushort_t* __restrict__ tgt, int* __restrict__ flag) {
    __shared__ int red[256];
    const int tid = threadIdx.x;
    int p = 0;
    for (int i = tid; i < 512; i += 256) {
        ushort_t u = tgt[i];
        int e = (u >> 7) & 0xFF;
        if (u == 0 || (e >= 100 && e <= 140)) ++p;
    }
    red[tid] = p; __syncthreads();
    for (int off = 128; off > 0; off >>= 1) {
        if (tid < off) red[tid] += red[tid + off];
        __syncthreads();
    }
    if (tid == 0) flag[0] = (red[0] >= 480) ? 1 : 0;
}

// ---------------------------------------------------------------------------
// Unified prep (grid 32x32x13):
//   z 0..9 : weight transpose src[K][N] -> dst[N][K] bf16 via 64x64 LDS tile
//   z 10/11: tgt/mem -> bf16 (1024 blocks x 256 thr x 8 elems = 2M)
//   z 12   : biases -> packed f32 [6656] (first 26 linear blocks)
// ---------------------------------------------------------------------------
__global__ __launch_bounds__(256) void prep_all(
    const void* sWq, const void* sWk, const void* sWv, const void* sWo,
    const void* cWq, const void* cWk, const void* cWv, const void* cWo,
    const void* fW1, const void* fW2,
    const void* tgt, const void* mem,
    const void* sbq, const void* sbk, const void* sbv, const void* sbo,
    const void* cbq, const void* cbk, const void* cbv, const void* cbo,
    const void* fb1, const void* fb2,
    ushort_t* __restrict__ wb, ushort_t* __restrict__ tb, ushort_t* __restrict__ mb,
    float* __restrict__ pb, const int* __restrict__ dflag)
{
    const bool f32 = (dflag[0] == 0);
    const int tid = threadIdx.x;
    const int z = blockIdx.z;

    if (z < 10) {
        const void* src; ushort_t* dst; int Kd, Nd;
        switch (z) {
            case 0: src = sWq; dst = wb + 0;       Kd = 512;  Nd = 512;  break;
            case 1: src = sWk; dst = wb + 262144;  Kd = 512;  Nd = 512;  break;
            case 2: src = sWv; dst = wb + 524288;  Kd = 512;  Nd = 512;  break;
            case 3: src = sWo; dst = wb + 786432;  Kd = 512;  Nd = 512;  break;
            case 4: src = cWq; dst = wb + 1048576; Kd = 512;  Nd = 512;  break;
            case 5: src = cWk; dst = wb + 1310720; Kd = 512;  Nd = 512;  break;
            case 6: src = cWv; dst = wb + 1572864; Kd = 512;  Nd = 512;  break;
            case 7: src = cWo; dst = wb + 1835008; Kd = 512;  Nd = 512;  break;
            case 8: src = fW1; dst = wb + 2097152; Kd = 512;  Nd = 2048; break;
            default:src = fW2; dst = wb + 3145728; Kd = 2048; Nd = 512;  break;
        }
        const int k0 = blockIdx.x * 64, n0 = blockIdx.y * 64;
        if (k0 >= Kd || n0 >= Nd) return;
        __shared__ ushort_t T[64][65];
#pragma unroll
        for (int i = 0; i < 16; ++i) {
            int j = i * 256 + tid;
            int r = j >> 6, c = j & 63;
            float v = f32 ? ((const float*)src)[(size_t)(k0 + r) * Nd + n0 + c]
                          : bf2f(((const ushort_t*)src)[(size_t)(k0 + r) * Nd + n0 + c]);
            T[r][c] = f2bf(v);
        }
        __syncthreads();
#pragma unroll
        for (int i = 0; i < 16; ++i) {
            int j = i * 256 + tid;
            int n = j >> 6, k = j & 63;
            dst[(size_t)(n0 + n) * Kd + k0 + k] = T[k][n];
        }
        return;
    }

    const int bid = blockIdx.x * 32 + blockIdx.y;
    if (z < 12) {
        const void* src = (z == 10) ? tgt : mem;
        ushort_t* dst = (z == 10) ? tb : mb;
        const int i = (bid * 256 + tid) * 8;
        if (f32) {
            float4 v0 = *(const float4*)((const float*)src + i);
            float4 v1 = *(const float4*)((const float*)src + i + 4);
            ushort_t o[8] = { f2bf(v0.x), f2bf(v0.y), f2bf(v0.z), f2bf(v0.w),
                              f2bf(v1.x), f2bf(v1.y), f2bf(v1.z), f2bf(v1.w) };
            *(uint4*)(dst + i) = *(const uint4*)o;
        } else {
            *(uint4*)(dst + i) = *(const uint4*)((const ushort_t*)src + i);
        }
        return;
    }

    {   // z == 12: biases
        const int i = bid * 256 + tid;
        if (bid >= 26 || i >= 6656) return;
        const void* src; int off;
        if      (i < 512)  { src = sbq; off = i; }
        else if (i < 1024) { src = sbk; off = i - 512; }
        else if (i < 1536) { src = sbv; off = i - 1024; }
        else if (i < 2048) { src = sbo; off = i - 1536; }
        else if (i < 2560) { src = cbq; off = i - 2048; }
        else if (i < 3072) { src = cbk; off = i - 2560; }
        else if (i < 3584) { src = cbv; off = i - 3072; }
        else if (i < 4096) { src = cbo; off = i - 3584; }
        else if (i < 6144) { src = fb1; off = i - 4096; }
        else               { src = fb2; off = i - 6144; }
        pb[i] = f32 ? ((const float*)src)[off] : bf2f(((const ushort_t*)src)[off]);
    }
}

// ---------------------------------------------------------------------------
// GEMM: unchanged from round 10 (dbuf neutral vs round 9; keeping for
// attribution — GEMM is at its per-shape plateau per m99/m100 analog).
// ---------------------------------------------------------------------------
template<typename OutT, bool RELU, int BN>
__global__ __launch_bounds__(256) void gemm_tn(
    const ushort_t* __restrict__ A1, const ushort_t* __restrict__ A2,
    int ySplit, int lda,
    const ushort_t* __restrict__ Wt, int ldw,
    const float* __restrict__ bias,
    OutT* __restrict__ C, int ldc, int K)
{
    constexpr int MI = (BN == 128) ? 4 : 2;
    __shared__ ushort_t As[2][128][32];
    __shared__ ushort_t Bs[2][BN][32];
    const int tid = threadIdx.x;
    const int wave = tid >> 6, lane = tid & 63;
    const int quad = lane >> 4, l16 = lane & 15;
    const int m0 = blockIdx.x * 128, n0 = blockIdx.y * BN;
    const int wm = (BN == 128) ? (wave >> 1) * 64 : wave * 32;
    const int wn = (BN == 128) ? (wave & 1) * 64 : 0;
    const ushort_t* A = (((int)blockIdx.y) < ySplit) ? A1 : A2;

    float4v acc[MI][4];
#pragma unroll
    for (int mi = 0; mi < MI; ++mi)
#pragma unroll
        for (int ni = 0; ni < 4; ++ni) {
            acc[mi][ni][0] = 0.f; acc[mi][ni][1] = 0.f;
            acc[mi][ni][2] = 0.f; acc[mi][ni][3] = 0.f;
        }

    const int srow = lane >> 2;
    const int scc  = lane & 3;
    const int sg   = (scc - (lane >> 3)) & 3;
    const ushort_t* aptr0 = A  + (size_t)(m0 + wave * 16 + srow) * lda + sg * 8;
    const ushort_t* aptr1 = A  + (size_t)(m0 + 64 + wave * 16 + srow) * lda + sg * 8;
    const ushort_t* bptr0 = Wt + (size_t)(n0 + wave * 16 + srow) * ldw + sg * 8;
    const ushort_t* bptr1 = Wt + (size_t)(n0 + 64 + wave * 16 + srow) * ldw + sg * 8;

    gll16(aptr0, &As[0][wave * 16][0]);
    gll16(aptr1, &As[0][64 + wave * 16][0]);
    gll16(bptr0, &Bs[0][wave * 16][0]);
    if (BN == 128) gll16(bptr1, &Bs[0][64 + wave * 16][0]);

    const int ca = ((quad + (l16 >> 1)) & 3) * 8;
    int cur = 0;
    for (int k0 = 0; k0 < K; k0 += 32) {
        __syncthreads();
        if (k0 + 32 < K) {
            const int nb = cur ^ 1, ko = k0 + 32;
            gll16(aptr0 + ko, &As[nb][wave * 16][0]);
            gll16(aptr1 + ko, &As[nb][64 + wave * 16][0]);
            gll16(bptr0 + ko, &Bs[nb][wave * 16][0]);
            if (BN == 128) gll16(bptr1 + ko, &Bs[nb][64 + wave * 16][0]);
        }
        short8 af[MI], bfr[4];
#pragma unroll
        for (int mi = 0; mi < MI; ++mi)
            af[mi] = *(const short8*)(&As[cur][wm + mi * 16 + l16][ca]);
#pragma unroll
        for (int ni = 0; ni < 4; ++ni)
            bfr[ni] = *(const short8*)(&Bs[cur][wn + ni * 16 + l16][ca]);
#pragma unroll
        for (int mi = 0; mi < MI; ++mi)
#pragma unroll
            for (int ni = 0; ni < 4; ++ni)
                acc[mi][ni] = __builtin_amdgcn_mfma_f32_16x16x32_bf16(
                    af[mi], bfr[ni], acc[mi][ni], 0, 0, 0);
        cur ^= 1;
    }

#pragma unroll
    for (int ni = 0; ni < 4; ++ni) {
        const int col = n0 + wn + ni * 16 + l16;
        const float bv = bias[col];
#pragma unroll
        for (int mi = 0; mi < MI; ++mi)
#pragma unroll
            for (int r = 0; r < 4; ++r) {
                const int row = m0 + wm + mi * 16 + quad * 4 + r;
                float v = acc[mi][ni][r] + bv;
                if (RELU) v = fmaxf(v, 0.f);
                store_out(&C[(size_t)row * ldc + col], v);
            }
    }
}

// ---------------------------------------------------------------------------
// Flash attention (MFMA) over packed qkv [4096][1536]. Fixed-reference
// streaming softmax. Round-11 changes:
//  (1) REGISTER PREFETCH: tile k+1's K/V global loads are issued right after
//      the compute barrier and consumed (reg->LDS) at iteration k+1's staging
//      phase — load latency overlaps the whole QK/softmax/PV phase instead of
//      being exposed between the two barriers.
//  (2) Ps aliases Qs (Qs dead after Q-fragments are register-resident; loop
//      barriers guarantee all waves read Qs first) — LDS 36->27 KB, 4->5
//      blocks/CU.
// O written in-place over Q (block-disjoint tiles).
// ---------------------------------------------------------------------------
__global__ __launch_bounds__(256) void attn_mfma(ushort_t* __restrict__ QKV)
{
    const int S = 1536;
    __shared__ ushort_t Qs[64][72];      // reused as P tiles after Q frag read
    __shared__ ushort_t Ks[64][72];
    __shared__ ushort_t Vt[64][72];

    const int tid  = threadIdx.x;
    const int wave = tid >> 6, lane = tid & 63;
    const int quad = lane >> 4, l16 = lane & 15;
    const int qt = blockIdx.x, bh = blockIdx.y;
    const int b = bh >> 3, h = bh & 7;
    const size_t rowQ = (size_t)b * 1024 + qt * 64;
    const size_t kv0  = (size_t)b * 1024;

    // staging coordinates
    const int kr = tid >> 2, kc = (tid & 3) * 16;   // K: row, 16-col chunk
    const int sp = tid >> 3, dc = (tid & 7) * 8;    // V: s-pair, 8-d chunk
    const int vr0 = sp * 2;
    const int vrg = vr0 >> 3, vrof = vr0 & 7;

    {   // stage Q tile
        const ushort_t* src = QKV + (rowQ + kr) * S + h * 64 + kc;
        *(uint4*)(&Qs[kr][kc])     = *(const uint4*)(src);
        *(uint4*)(&Qs[kr][kc + 8]) = *(const uint4*)(src + 8);
    }
    __syncthreads();
    short8 qf[2];
    qf[0] = *(const short8*)(&Qs[wave * 16 + l16][quad * 8]);
    qf[1] = *(const short8*)(&Qs[wave * 16 + l16][32 + quad * 8]);
    ushort_t (* __restrict__ Ps)[72] = Qs;   // alias: row = wave*16 + qrow

    const float CEXP = 0.125f * 1.44269504f;   // head-scale * log2(e)
    const float MREF = 16.0f * CEXP;           // fixed softmax reference
    float lsum[4];
    float4v oacc[4];
#pragma unroll
    for (int r = 0; r < 4; ++r) lsum[r] = 0.f;
#pragma unroll
    for (int n = 0; n < 4; ++n) { oacc[n][0]=0.f; oacc[n][1]=0.f; oacc[n][2]=0.f; oacc[n][3]=0.f; }

    // prefetch tile 0 K/V into registers
    uint4 kA, kB, vA, vB;
    {
        const ushort_t* ksrc = QKV + (kv0 + kr) * S + 512 + h * 64 + kc;
        kA = *(const uint4*)(ksrc);
        kB = *(const uint4*)(ksrc + 8);
        const ushort_t* vsrc = QKV + (kv0 + vr0) * S + 1024 + h * 64 + dc;
        vA = *(const uint4*)(vsrc);
        vB = *(const uint4*)(vsrc + S);
    }

    for (int s0 = 0; s0 < 1024; s0 += 64) {
        __syncthreads();   // prior iteration finished reading Ks/Vt/Ps
        // regs -> LDS
        *(uint4*)(&Ks[kr][kc])     = kA;
        *(uint4*)(&Ks[kr][kc + 8]) = kB;
        {
            const ushort_t* ae = (const ushort_t*)&vA;
            const ushort_t* be = (const ushort_t*)&vB;
#pragma unroll
            for (int j = 0; j < 8; ++j) {
                const int d = dc + j;
                const int cc = (vrg ^ (d >> 4)) & 7;
                *(unsigned int*)(&Vt[d][cc * 8 + vrof]) =
                    (unsigned int)ae[j] | ((unsigned int)be[j] << 16);
            }
        }
        __syncthreads();
        // issue next tile's global loads — consumed only at next staging phase
        if (s0 + 64 < 1024) {
            const ushort_t* ksrc = QKV + (kv0 + s0 + 64 + kr) * S + 512 + h * 64 + kc;
            kA = *(const uint4*)(ksrc);
            kB = *(const uint4*)(ksrc + 8);
            const ushort_t* vsrc = QKV + (kv0 + s0 + 64 + vr0) * S + 1024 + h * 64 + dc;
            vA = *(const uint4*)(vsrc);
            vB = *(const uint4*)(vsrc + S);
        }

        // QK^T
        float4v sc[4];
#pragma unroll
        for (int sb = 0; sb < 4; ++sb) {
            float4v z; z[0]=0.f; z[1]=0.f; z[2]=0.f; z[3]=0.f;
            short8 kf0 = *(const short8*)(&Ks[sb * 16 + l16][quad * 8]);
            short8 kf1 = *(const short8*)(&Ks[sb * 16 + l16][32 + quad * 8]);
            z = __builtin_amdgcn_mfma_f32_16x16x32_bf16(qf[0], kf0, z, 0, 0, 0);
            z = __builtin_amdgcn_mfma_f32_16x16x32_bf16(qf[1], kf1, z, 0, 0, 0);
            sc[sb] = z;
        }

        // streaming softmax, fixed reference
#pragma unroll
        for (int sb = 0; sb < 4; ++sb)
#pragma unroll
            for (int r = 0; r < 4; ++r) {
                float p = exp2f(fmaf(sc[sb][r], CEXP, -MREF));
                lsum[r] += p;
                Ps[wave * 16 + quad * 4 + r][sb * 16 + l16] = f2bf(p);
            }

        // PV
        short8 pf[2];
        pf[0] = *(const short8*)(&Ps[wave * 16 + l16][quad * 8]);
        pf[1] = *(const short8*)(&Ps[wave * 16 + l16][32 + quad * 8]);
#pragma unroll
        for (int n = 0; n < 4; ++n) {
#pragma unroll
            for (int kc2 = 0; kc2 < 2; ++kc2) {
                const int cc = ((kc2 * 4 + quad) ^ n) & 7;
                short8 vf = *(const short8*)(&Vt[n * 16 + l16][cc * 8]);
                oacc[n] = __builtin_amdgcn_mfma_f32_16x16x32_bf16(pf[kc2], vf, oacc[n], 0, 0, 0);
            }
        }
    }

    // single final l reduction across the 16 s-lanes of each quad-group
#pragma unroll
    for (int msk = 1; msk < 16; msk <<= 1)
#pragma unroll
        for (int r = 0; r < 4; ++r) lsum[r] += __shfl_xor(lsum[r], msk);
    float inv[4];
#pragma unroll
    for (int r = 0; r < 4; ++r) inv[r] = 1.f / lsum[r];
#pragma unroll
    for (int n = 0; n < 4; ++n)
#pragma unroll
        for (int r = 0; r < 4; ++r) {
            const size_t row = rowQ + wave * 16 + quad * 4 + r;
            QKV[row * S + h * 64 + n * 16 + l16] = f2bf(oacc[n][r] * inv[r]);
        }
}

// ---------------------------------------------------------------------------
// LayerNorm over E=512, wave-shuffle reductions (2 barriers).
// ---------------------------------------------------------------------------
template<bool RES_EXT, bool DELTA_F32, bool OUT_FLAG>
__global__ __launch_bounds__(256) void ln_kernel(
    const void* __restrict__ res, const void* __restrict__ delta,
    const void* __restrict__ g, const void* __restrict__ be,
    void* __restrict__ out, const int* __restrict__ dflag)
{
    const int E = 512;
    const bool extf32 = (dflag[0] == 0);
    const int row = blockIdx.x, tid = threadIdx.x;
    const int wave = tid >> 6, lane = tid & 63;
    const size_t base = (size_t)row * E;
    const int i0 = tid, i1 = tid + 256;

    float r0, r1;
    if (RES_EXT && extf32) {
        r0 = ((const float*)res)[base + i0];
        r1 = ((const float*)res)[base + i1];
    } else {
        r0 = bf2f(((const ushort_t*)res)[base + i0]);
        r1 = bf2f(((const ushort_t*)res)[base + i1]);
    }
    float d0v, d1v;
    if (DELTA_F32) {
        d0v = ((const float*)delta)[base + i0];
        d1v = ((const float*)delta)[base + i1];
    } else {
        d0v = bf2f(((const ushort_t*)delta)[base + i0]);
        d1v = bf2f(((const ushort_t*)delta)[base + i1]);
    }
    float x0 = r0 + d0v, x1 = r1 + d1v;

    __shared__ float red8[8];
    float s = x0 + x1;
#pragma unroll
    for (int m = 1; m < 64; m <<= 1) s += __shfl_xor(s, m);
    if (lane == 0) red8[wave] = s;
    __syncthreads();
    float mean = (red8[0] + red8[1] + red8[2] + red8[3]) * (1.0f / 512.0f);
    float dd0 = x0 - mean, dd1 = x1 - mean;
    float v = dd0 * dd0 + dd1 * dd1;
#pragma unroll
    for (int m = 1; m < 64; m <<= 1) v += __shfl_xor(v, m);
    if (lane == 0) red8[4 + wave] = v;
    __syncthreads();
    float rstd = rsqrtf((red8[4] + red8[5] + red8[6] + red8[7]) * (1.0f / 512.0f) + 1e-5f);

    float g0, g1v, b0, b1;
    if (extf32) {
        g0 = ((const float*)g)[i0];  g1v = ((const float*)g)[i1];
        b0 = ((const float*)be)[i0]; b1  = ((const float*)be)[i1];
    } else {
        g0 = bf2f(((const ushort_t*)g)[i0]);  g1v = bf2f(((const ushort_t*)g)[i1]);
        b0 = bf2f(((const ushort_t*)be)[i0]); b1  = bf2f(((const ushort_t*)be)[i1]);
    }
    float y0 = dd0 * rstd * g0 + b0;
    float y1 = dd1 * rstd * g1v + b1;
    if (OUT_FLAG && extf32) {
        ((float*)out)[base + i0] = y0; ((float*)out)[base + i1] = y1;
    } else {
        ((ushort_t*)out)[base + i0] = f2bf(y0);
        ((ushort_t*)out)[base + i1] = f2bf(y1);
    }
}

// ---------------------------------------------------------------------------
// Workspace (~36.3 MiB):
//   [ 0 ..12M) qkv bf16 [4096][1536]   } FFN phase: hb bf16 [4096][2048]
//   [12M..16M) po  bf16 [4096][512]    }   occupies [0..16M)
//   [16M..20M) xb  bf16 [4096][512]  (residual, live through FFN)
//   [20M..24M) tb  bf16 (tgt)   } FFN phase: of f32 [4096][512] at [20..28M)
//   [24M..28M) mb  bf16 (mem)   }
//   [28M..36M) wb  bf16 transposed weights
//   [36M..]    pb  f32 packed biases; dflag at +256K
// ---------------------------------------------------------------------------

extern "C" void kernel_launch(void* const* d_in, const int* in_sizes, int n_in,
                              void* d_out, int out_size, void* d_ws, size_t ws_size,
                              hipStream_t stream) {
    const void* tgt = d_in[0];
    const void* mem = d_in[1];
    const void* sWq = d_in[2];  const void* sWk = d_in[3];
    const void* sWv = d_in[4];  const void* sWo = d_in[5];
    const void* cWq = d_in[6];  const void* cWk = d_in[7];
    const void* cWv = d_in[8];  const void* cWo = d_in[9];
    const void* sbq = d_in[10]; const void* sbk = d_in[11];
    const void* sbv = d_in[12]; const void* sbo = d_in[13];
    const void* cbq = d_in[14]; const void* cbk = d_in[15];
    const void* cbv = d_in[16]; const void* cbo = d_in[17];
    const void* fW1 = d_in[18]; const void* fb1 = d_in[19];
    const void* fW2 = d_in[20]; const void* fb2 = d_in[21];
    const void* g1  = d_in[22]; const void* g2  = d_in[23];
    const void* g3  = d_in[24];
    const void* be1 = d_in[25]; const void* be2 = d_in[26];
    const void* be3 = d_in[27];

    char* ws = (char*)d_ws;
    const size_t MB = 1048576;
    ushort_t* qkv = (ushort_t*)(ws + 0 * MB);
    ushort_t* hb  = (ushort_t*)(ws + 0 * MB);    // FFN hidden [4096][2048]
    ushort_t* po  = (ushort_t*)(ws + 12 * MB);
    ushort_t* xb  = (ushort_t*)(ws + 16 * MB);
    ushort_t* tb  = (ushort_t*)(ws + 20 * MB);
    ushort_t* mb  = (ushort_t*)(ws + 24 * MB);
    float*    of  = (float*)   (ws + 20 * MB);   // FFN out f32 [4096][512]
    ushort_t* wb  = (ushort_t*)(ws + 28 * MB);
    float*    pb  = (float*)   (ws + 36 * MB);
    int*   dflag  = (int*)     (ws + 36 * MB + 262144);

    const ushort_t* sWqkv_t = wb + 0;
    const ushort_t* sWo_t   = wb + 786432;
    const ushort_t* cWqkv_t = wb + 1048576;   // cWq_t|cWk_t|cWv_t contiguous
    const ushort_t* cWo_t   = wb + 1835008;
    const ushort_t* fW1_t   = wb + 2097152;
    const ushort_t* fW2_t   = wb + 3145728;

    dim3 blk(256);

    // ---- prep ----
    detect_dtype<<<dim3(1), blk, 0, stream>>>((const ushort_t*)tgt, dflag);
    prep_all<<<dim3(32, 32, 13), blk, 0, stream>>>(
        sWq, sWk, sWv, sWo, cWq, cWk, cWv, cWo, fW1, fW2,
        tgt, mem, sbq, sbk, sbv, sbo, cbq, cbk, cbv, cbo, fb1, fb2,
        wb, tb, mb, pb, dflag);

    dim3 gattn(16, 32);

    // ---- self-attention ----
    gemm_tn<ushort_t, false, 128><<<dim3(32, 12), blk, 0, stream>>>(tb, tb, 0, 512, sWqkv_t, 512, pb + 0, qkv, 1536, 512);
    attn_mfma<<<gattn, blk, 0, stream>>>(qkv);
    gemm_tn<ushort_t, false, 64><<<dim3(32, 8), blk, 0, stream>>>(qkv, qkv, 0, 1536, sWo_t, 512, pb + 1536, po, 512, 512);
    ln_kernel<true, false, false><<<dim3(4096), blk, 0, stream>>>(tgt, po, g1, be1, xb, dflag);

    // ---- cross-attention (Q-proj and KV-proj fused into one dispatch) ----
    gemm_tn<ushort_t, false, 128><<<dim3(32, 12), blk, 0, stream>>>(xb, mb, 4, 512, cWqkv_t, 512, pb + 2048, qkv, 1536, 512);
    attn_mfma<<<gattn, blk, 0, stream>>>(qkv);
    gemm_tn<ushort_t, false, 64><<<dim3(32, 8), blk, 0, stream>>>(qkv, qkv, 0, 1536, cWo_t, 512, pb + 3584, po, 512, 512);
    ln_kernel<false, false, false><<<dim3(4096), blk, 0, stream>>>(xb, po, g2, be2, xb, dflag);

    // ---- FFN: full-width, single pass each ----
    gemm_tn<ushort_t, true, 128><<<dim3(32, 16), blk, 0, stream>>>(xb, xb, 0, 512, fW1_t, 512, pb + 4096, hb, 2048, 512);
    gemm_tn<float, false, 64><<<dim3(32, 8), blk, 0, stream>>>(hb, hb, 0, 2048, fW2_t, 2048, pb + 6144, of, 512, 2048);
    ln_kernel<false, true, true><<<dim3(4096), blk, 0, stream>>>(xb, of, g3, be3, d_out, dflag);
}

// Round 12
// 299.341 us; speedup vs baseline: 1.0389x; 1.0206x over previous
//
#include <hip/hip_runtime.h>

typedef unsigned short ushort_t;
typedef short short8 __attribute__((ext_vector_type(8)));
typedef float float4v __attribute__((ext_vector_type(4)));

__device__ __forceinline__ float bf2f(ushort_t u) {
    union { unsigned int i; float f; } x; x.i = ((unsigned int)u) << 16; return x.f;
}
__device__ __forceinline__ ushort_t f2bf(float f) {
    unsigned int u = __float_as_uint(f);
    unsigned int r = (u + 0x7FFFu + ((u >> 16) & 1u)) >> 16;
    return (ushort_t)r;
}
__device__ __forceinline__ void store_out(float* p, float v) { *p = v; }
__device__ __forceinline__ void store_out(ushort_t* p, float v) { *p = f2bf(v); }

// async global->LDS 16B/lane; lds ptr must be wave-uniform base (lane*16 auto)
__device__ __forceinline__ void gll16(const ushort_t* g, ushort_t* l) {
    __builtin_amdgcn_global_load_lds(
        (const __attribute__((address_space(1))) void*)g,
        (__attribute__((address_space(3))) void*)l, 16, 0, 0);
}

// ---------------------------------------------------------------------------
// Input-dtype detection. flag=1 -> inputs bf16; flag=0 -> inputs f32.
// ---------------------------------------------------------------------------
__global__ void detect_dtype(const ushort_t* __restrict__ tgt, int* __restrict__ flag) {
    __shared__ int red[256];
    const int tid = threadIdx.x;
    int p = 0;
    for (int i = tid; i < 512; i += 256) {
        ushort_t u = tgt[i];
        int e = (u >> 7) & 0xFF;
        if (u == 0 || (e >= 100 && e <= 140)) ++p;
    }
    red[tid] = p; __syncthreads();
    for (int off = 128; off > 0; off >>= 1) {
        if (tid < off) red[tid] += red[tid + off];
        __syncthreads();
    }
    if (tid == 0) flag[0] = (red[0] >= 480) ? 1 : 0;
}

// ---------------------------------------------------------------------------
// Unified prep (grid 32x32x13):
//   z 0..9 : weight transpose src[K][N] -> dst[N][K] bf16 via 64x64 LDS tile
//   z 10/11: tgt/mem -> bf16
//   z 12   : biases -> packed f32 [6656]
// ---------------------------------------------------------------------------
__global__ __launch_bounds__(256) void prep_all(
    const void* sWq, const void* sWk, const void* sWv, const void* sWo,
    const void* cWq, const void* cWk, const void* cWv, const void* cWo,
    const void* fW1, const void* fW2,
    const void* tgt, const void* mem,
    const void* sbq, const void* sbk, const void* sbv, const void* sbo,
    const void* cbq, const void* cbk, const void* cbv, const void* cbo,
    const void* fb1, const void* fb2,
    ushort_t* __restrict__ wb, ushort_t* __restrict__ tb, ushort_t* __restrict__ mb,
    float* __restrict__ pb, const int* __restrict__ dflag)
{
    const bool f32 = (dflag[0] == 0);
    const int tid = threadIdx.x;
    const int z = blockIdx.z;

    if (z < 10) {
        const void* src; ushort_t* dst; int Kd, Nd;
        switch (z) {
            case 0: src = sWq; dst = wb + 0;       Kd = 512;  Nd = 512;  break;
            case 1: src = sWk; dst = wb + 262144;  Kd = 512;  Nd = 512;  break;
            case 2: src = sWv; dst = wb + 524288;  Kd = 512;  Nd = 512;  break;
            case 3: src = sWo; dst = wb + 786432;  Kd = 512;  Nd = 512;  break;
            case 4: src = cWq; dst = wb + 1048576; Kd = 512;  Nd = 512;  break;
            case 5: src = cWk; dst = wb + 1310720; Kd = 512;  Nd = 512;  break;
            case 6: src = cWv; dst = wb + 1572864; Kd = 512;  Nd = 512;  break;
            case 7: src = cWo; dst = wb + 1835008; Kd = 512;  Nd = 512;  break;
            case 8: src = fW1; dst = wb + 2097152; Kd = 512;  Nd = 2048; break;
            default:src = fW2; dst = wb + 3145728; Kd = 2048; Nd = 512;  break;
        }
        const int k0 = blockIdx.x * 64, n0 = blockIdx.y * 64;
        if (k0 >= Kd || n0 >= Nd) return;
        __shared__ ushort_t T[64][65];
#pragma unroll
        for (int i = 0; i < 16; ++i) {
            int j = i * 256 + tid;
            int r = j >> 6, c = j & 63;
            float v = f32 ? ((const float*)src)[(size_t)(k0 + r) * Nd + n0 + c]
                          : bf2f(((const ushort_t*)src)[(size_t)(k0 + r) * Nd + n0 + c]);
            T[r][c] = f2bf(v);
        }
        __syncthreads();
#pragma unroll
        for (int i = 0; i < 16; ++i) {
            int j = i * 256 + tid;
            int n = j >> 6, k = j & 63;
            dst[(size_t)(n0 + n) * Kd + k0 + k] = T[k][n];
        }
        return;
    }

    const int bid = blockIdx.x * 32 + blockIdx.y;
    if (z < 12) {
        const void* src = (z == 10) ? tgt : mem;
        ushort_t* dst = (z == 10) ? tb : mb;
        const int i = (bid * 256 + tid) * 8;
        if (f32) {
            float4 v0 = *(const float4*)((const float*)src + i);
            float4 v1 = *(const float4*)((const float*)src + i + 4);
            ushort_t o[8] = { f2bf(v0.x), f2bf(v0.y), f2bf(v0.z), f2bf(v0.w),
                              f2bf(v1.x), f2bf(v1.y), f2bf(v1.z), f2bf(v1.w) };
            *(uint4*)(dst + i) = *(const uint4*)o;
        } else {
            *(uint4*)(dst + i) = *(const uint4*)((const ushort_t*)src + i);
        }
        return;
    }

    {   // z == 12: biases
        const int i = bid * 256 + tid;
        if (bid >= 26 || i >= 6656) return;
        const void* src; int off;
        if      (i < 512)  { src = sbq; off = i; }
        else if (i < 1024) { src = sbk; off = i - 512; }
        else if (i < 1536) { src = sbv; off = i - 1024; }
        else if (i < 2048) { src = sbo; off = i - 1536; }
        else if (i < 2560) { src = cbq; off = i - 2048; }
        else if (i < 3072) { src = cbk; off = i - 2560; }
        else if (i < 3584) { src = cbv; off = i - 3072; }
        else if (i < 4096) { src = cbo; off = i - 3584; }
        else if (i < 6144) { src = fb1; off = i - 4096; }
        else               { src = fb2; off = i - 6144; }
        pb[i] = f32 ? ((const float*)src)[off] : bf2f(((const ushort_t*)src)[off]);
    }
}

// ---------------------------------------------------------------------------
// GEMM: unchanged from round 10/11 (at its per-shape plateau).
// ---------------------------------------------------------------------------
template<typename OutT, bool RELU, int BN>
__global__ __launch_bounds__(256) void gemm_tn(
    const ushort_t* __restrict__ A1, const ushort_t* __restrict__ A2,
    int ySplit, int lda,
    const ushort_t* __restrict__ Wt, int ldw,
    const float* __restrict__ bias,
    OutT* __restrict__ C, int ldc, int K)
{
    constexpr int MI = (BN == 128) ? 4 : 2;
    __shared__ ushort_t As[2][128][32];
    __shared__ ushort_t Bs[2][BN][32];
    const int tid = threadIdx.x;
    const int wave = tid >> 6, lane = tid & 63;
    const int quad = lane >> 4, l16 = lane & 15;
    const int m0 = blockIdx.x * 128, n0 = blockIdx.y * BN;
    const int wm = (BN == 128) ? (wave >> 1) * 64 : wave * 32;
    const int wn = (BN == 128) ? (wave & 1) * 64 : 0;
    const ushort_t* A = (((int)blockIdx.y) < ySplit) ? A1 : A2;

    float4v acc[MI][4];
#pragma unroll
    for (int mi = 0; mi < MI; ++mi)
#pragma unroll
        for (int ni = 0; ni < 4; ++ni) {
            acc[mi][ni][0] = 0.f; acc[mi][ni][1] = 0.f;
            acc[mi][ni][2] = 0.f; acc[mi][ni][3] = 0.f;
        }

    const int srow = lane >> 2;
    const int scc  = lane & 3;
    const int sg   = (scc - (lane >> 3)) & 3;
    const ushort_t* aptr0 = A  + (size_t)(m0 + wave * 16 + srow) * lda + sg * 8;
    const ushort_t* aptr1 = A  + (size_t)(m0 + 64 + wave * 16 + srow) * lda + sg * 8;
    const ushort_t* bptr0 = Wt + (size_t)(n0 + wave * 16 + srow) * ldw + sg * 8;
    const ushort_t* bptr1 = Wt + (size_t)(n0 + 64 + wave * 16 + srow) * ldw + sg * 8;

    gll16(aptr0, &As[0][wave * 16][0]);
    gll16(aptr1, &As[0][64 + wave * 16][0]);
    gll16(bptr0, &Bs[0][wave * 16][0]);
    if (BN == 128) gll16(bptr1, &Bs[0][64 + wave * 16][0]);

    const int ca = ((quad + (l16 >> 1)) & 3) * 8;
    int cur = 0;
    for (int k0 = 0; k0 < K; k0 += 32) {
        __syncthreads();
        if (k0 + 32 < K) {
            const int nb = cur ^ 1, ko = k0 + 32;
            gll16(aptr0 + ko, &As[nb][wave * 16][0]);
            gll16(aptr1 + ko, &As[nb][64 + wave * 16][0]);
            gll16(bptr0 + ko, &Bs[nb][wave * 16][0]);
            if (BN == 128) gll16(bptr1 + ko, &Bs[nb][64 + wave * 16][0]);
        }
        short8 af[MI], bfr[4];
#pragma unroll
        for (int mi = 0; mi < MI; ++mi)
            af[mi] = *(const short8*)(&As[cur][wm + mi * 16 + l16][ca]);
#pragma unroll
        for (int ni = 0; ni < 4; ++ni)
            bfr[ni] = *(const short8*)(&Bs[cur][wn + ni * 16 + l16][ca]);
#pragma unroll
        for (int mi = 0; mi < MI; ++mi)
#pragma unroll
            for (int ni = 0; ni < 4; ++ni)
                acc[mi][ni] = __builtin_amdgcn_mfma_f32_16x16x32_bf16(
                    af[mi], bfr[ni], acc[mi][ni], 0, 0, 0);
        cur ^= 1;
    }

#pragma unroll
    for (int ni = 0; ni < 4; ++ni) {
        const int col = n0 + wn + ni * 16 + l16;
        const float bv = bias[col];
#pragma unroll
        for (int mi = 0; mi < MI; ++mi)
#pragma unroll
            for (int r = 0; r < 4; ++r) {
                const int row = m0 + wm + mi * 16 + quad * 4 + r;
                float v = acc[mi][ni][r] + bv;
                if (RELU) v = fmaxf(v, 0.f);
                store_out(&C[(size_t)row * ldc + col], v);
            }
    }
}

// ---------------------------------------------------------------------------
// Flash attention (MFMA), 512 threads / 8 waves, INTRA-BLOCK SPLIT-S:
// waves 0-3 (group 0) process even 64-s-tiles, waves 4-7 (group 1) odd
// tiles; wave w owns q-rows [(w&3)*16, +16). Fixed-reference softmax makes
// partials exactly summable: O = (O_A + O_B) / (l_A + l_B). Doubles
// resident waves (25% -> 50% occupancy cap) and halves per-wave work.
// Per-group staging identical to round 11 (register prefetch). O in-place
// over Q (block-disjoint tiles).
// ---------------------------------------------------------------------------
__global__ __launch_bounds__(512) void attn_mfma(ushort_t* __restrict__ QKV)
{
    const int S = 1536;
    __shared__ ushort_t PsA[64][72];     // Q staging, then group-0 P tiles
    __shared__ ushort_t PsB[64][72];     // group-1 P tiles
    __shared__ ushort_t Ks[2][64][72];
    __shared__ ushort_t Vt[2][64][72];

    const int tid  = threadIdx.x;
    const int w    = tid >> 6;           // 0..7
    const int g    = w >> 2;             // s-parity group
    const int wq   = w & 3;              // q-subtile within group
    const int lane = tid & 63;
    const int quad = lane >> 4, l16 = lane & 15;
    const int ht   = tid & 255;          // within-group thread id
    const int qt = blockIdx.x, bh = blockIdx.y;
    const int b = bh >> 3, h = bh & 7;
    const size_t rowQ = (size_t)b * 1024 + qt * 64;
    const size_t kv0  = (size_t)b * 1024;

    // per-group staging coordinates (identical pattern to round 11)
    const int kr = ht >> 2, kc = (ht & 3) * 16;
    const int sp = ht >> 3, dc = (ht & 7) * 8;
    const int vr0 = sp * 2;
    const int vrg = vr0 >> 3, vrof = vr0 & 7;

    {   // stage Q tile: 512 threads x 1 uint4 = 64x64
        const int r = tid >> 3, c = (tid & 7) * 8;
        *(uint4*)(&PsA[r][c]) = *(const uint4*)(QKV + (rowQ + r) * S + h * 64 + c);
    }
    __syncthreads();
    short8 qf[2];
    qf[0] = *(const short8*)(&PsA[wq * 16 + l16][quad * 8]);
    qf[1] = *(const short8*)(&PsA[wq * 16 + l16][32 + quad * 8]);
    ushort_t (* __restrict__ Ps)[72] = g ? PsB : PsA;   // safe: 2 barriers before 1st P write

    const float CEXP = 0.125f * 1.44269504f;
    const float MREF = 16.0f * CEXP;
    float lsum[4];
    float4v oacc[4];
#pragma unroll
    for (int r = 0; r < 4; ++r) lsum[r] = 0.f;
#pragma unroll
    for (int n = 0; n < 4; ++n) { oacc[n][0]=0.f; oacc[n][1]=0.f; oacc[n][2]=0.f; oacc[n][3]=0.f; }

    // register prefetch of this group's first tile (s-base = g*64)
    uint4 kA, kB, vA, vB;
    {
        const size_t sr = kv0 + g * 64;
        const ushort_t* ksrc = QKV + (sr + kr) * S + 512 + h * 64 + kc;
        kA = *(const uint4*)(ksrc);
        kB = *(const uint4*)(ksrc + 8);
        const ushort_t* vsrc = QKV + (sr + vr0) * S + 1024 + h * 64 + dc;
        vA = *(const uint4*)(vsrc);
        vB = *(const uint4*)(vsrc + S);
    }

    for (int it = 0; it < 8; ++it) {
        __syncthreads();   // prior iteration finished reading Ks/Vt/Ps
        *(uint4*)(&Ks[g][kr][kc])     = kA;
        *(uint4*)(&Ks[g][kr][kc + 8]) = kB;
        {
            const ushort_t* ae = (const ushort_t*)&vA;
            const ushort_t* be = (const ushort_t*)&vB;
#pragma unroll
            for (int j = 0; j < 8; ++j) {
                const int d = dc + j;
                const int cc = (vrg ^ (d >> 4)) & 7;
                *(unsigned int*)(&Vt[g][d][cc * 8 + vrof]) =
                    (unsigned int)ae[j] | ((unsigned int)be[j] << 16);
            }
        }
        __syncthreads();
        if (it < 7) {   // prefetch next tile of this group
            const size_t sr = kv0 + (it + 1) * 128 + g * 64;
            const ushort_t* ksrc = QKV + (sr + kr) * S + 512 + h * 64 + kc;
            kA = *(const uint4*)(ksrc);
            kB = *(const uint4*)(ksrc + 8);
            const ushort_t* vsrc = QKV + (sr + vr0) * S + 1024 + h * 64 + dc;
            vA = *(const uint4*)(vsrc);
            vB = *(const uint4*)(vsrc + S);
        }

        // QK^T
        float4v sc[4];
#pragma unroll
        for (int sb = 0; sb < 4; ++sb) {
            float4v z; z[0]=0.f; z[1]=0.f; z[2]=0.f; z[3]=0.f;
            short8 kf0 = *(const short8*)(&Ks[g][sb * 16 + l16][quad * 8]);
            short8 kf1 = *(const short8*)(&Ks[g][sb * 16 + l16][32 + quad * 8]);
            z = __builtin_amdgcn_mfma_f32_16x16x32_bf16(qf[0], kf0, z, 0, 0, 0);
            z = __builtin_amdgcn_mfma_f32_16x16x32_bf16(qf[1], kf1, z, 0, 0, 0);
            sc[sb] = z;
        }

        // streaming softmax, fixed reference
#pragma unroll
        for (int sb = 0; sb < 4; ++sb)
#pragma unroll
            for (int r = 0; r < 4; ++r) {
                float p = exp2f(fmaf(sc[sb][r], CEXP, -MREF));
                lsum[r] += p;
                Ps[wq * 16 + quad * 4 + r][sb * 16 + l16] = f2bf(p);
            }

        // PV
        short8 pf[2];
        pf[0] = *(const short8*)(&Ps[wq * 16 + l16][quad * 8]);
        pf[1] = *(const short8*)(&Ps[wq * 16 + l16][32 + quad * 8]);
#pragma unroll
        for (int n = 0; n < 4; ++n) {
#pragma unroll
            for (int kc2 = 0; kc2 < 2; ++kc2) {
                const int cc = ((kc2 * 4 + quad) ^ n) & 7;
                short8 vf = *(const short8*)(&Vt[g][n * 16 + l16][cc * 8]);
                oacc[n] = __builtin_amdgcn_mfma_f32_16x16x32_bf16(pf[kc2], vf, oacc[n], 0, 0, 0);
            }
        }
    }

    // reduce lsum across the 16 s-lanes of each quad (masks 1..8 touch l16 only)
#pragma unroll
    for (int msk = 1; msk < 16; msk <<= 1)
#pragma unroll
        for (int r = 0; r < 4; ++r) lsum[r] += __shfl_xor(lsum[r], msk);

    // combine groups through LDS (reuse Ks as 16KB f32 exchange, Vt for lsum)
    float* exch = (float*)&Ks[0][0][0];
    float* exl  = (float*)&Vt[0][0][0];
    __syncthreads();   // all PV reads of Ks/Vt done
    if (g == 1) {
#pragma unroll
        for (int n = 0; n < 4; ++n)
#pragma unroll
            for (int r = 0; r < 4; ++r)
                exch[((wq * 4 + n) * 4 + r) * 64 + lane] = oacc[n][r];
        if (l16 == 0)
#pragma unroll
            for (int r = 0; r < 4; ++r) exl[wq * 16 + quad * 4 + r] = lsum[r];
    }
    __syncthreads();
    if (g == 0) {
#pragma unroll
        for (int r = 0; r < 4; ++r) lsum[r] += exl[wq * 16 + quad * 4 + r];
        float inv[4];
#pragma unroll
        for (int r = 0; r < 4; ++r) inv[r] = 1.f / lsum[r];
#pragma unroll
        for (int n = 0; n < 4; ++n)
#pragma unroll
            for (int r = 0; r < 4; ++r) {
                float o = oacc[n][r] + exch[((wq * 4 + n) * 4 + r) * 64 + lane];
                const size_t row = rowQ + wq * 16 + quad * 4 + r;
                QKV[row * S + h * 64 + n * 16 + l16] = f2bf(o * inv[r]);
            }
    }
}

// ---------------------------------------------------------------------------
// LayerNorm over E=512, wave-shuffle reductions (2 barriers).
// ---------------------------------------------------------------------------
template<bool RES_EXT, bool DELTA_F32, bool OUT_FLAG>
__global__ __launch_bounds__(256) void ln_kernel(
    const void* __restrict__ res, const void* __restrict__ delta,
    const void* __restrict__ g, const void* __restrict__ be,
    void* __restrict__ out, const int* __restrict__ dflag)
{
    const int E = 512;
    const bool extf32 = (dflag[0] == 0);
    const int row = blockIdx.x, tid = threadIdx.x;
    const int wave = tid >> 6, lane = tid & 63;
    const size_t base = (size_t)row * E;
    const int i0 = tid, i1 = tid + 256;

    float r0, r1;
    if (RES_EXT && extf32) {
        r0 = ((const float*)res)[base + i0];
        r1 = ((const float*)res)[base + i1];
    } else {
        r0 = bf2f(((const ushort_t*)res)[base + i0]);
        r1 = bf2f(((const ushort_t*)res)[base + i1]);
    }
    float d0v, d1v;
    if (DELTA_F32) {
        d0v = ((const float*)delta)[base + i0];
        d1v = ((const float*)delta)[base + i1];
    } else {
        d0v = bf2f(((const ushort_t*)delta)[base + i0]);
        d1v = bf2f(((const ushort_t*)delta)[base + i1]);
    }
    float x0 = r0 + d0v, x1 = r1 + d1v;

    __shared__ float red8[8];
    float s = x0 + x1;
#pragma unroll
    for (int m = 1; m < 64; m <<= 1) s += __shfl_xor(s, m);
    if (lane == 0) red8[wave] = s;
    __syncthreads();
    float mean = (red8[0] + red8[1] + red8[2] + red8[3]) * (1.0f / 512.0f);
    float dd0 = x0 - mean, dd1 = x1 - mean;
    float v = dd0 * dd0 + dd1 * dd1;
#pragma unroll
    for (int m = 1; m < 64; m <<= 1) v += __shfl_xor(v, m);
    if (lane == 0) red8[4 + wave] = v;
    __syncthreads();
    float rstd = rsqrtf((red8[4] + red8[5] + red8[6] + red8[7]) * (1.0f / 512.0f) + 1e-5f);

    float g0, g1v, b0, b1;
    if (extf32) {
        g0 = ((const float*)g)[i0];  g1v = ((const float*)g)[i1];
        b0 = ((const float*)be)[i0]; b1  = ((const float*)be)[i1];
    } else {
        g0 = bf2f(((const ushort_t*)g)[i0]);  g1v = bf2f(((const ushort_t*)g)[i1]);
        b0 = bf2f(((const ushort_t*)be)[i0]); b1  = bf2f(((const ushort_t*)be)[i1]);
    }
    float y0 = dd0 * rstd * g0 + b0;
    float y1 = dd1 * rstd * g1v + b1;
    if (OUT_FLAG && extf32) {
        ((float*)out)[base + i0] = y0; ((float*)out)[base + i1] = y1;
    } else {
        ((ushort_t*)out)[base + i0] = f2bf(y0);
        ((ushort_t*)out)[base + i1] = f2bf(y1);
    }
}

// ---------------------------------------------------------------------------
// Workspace (~36.3 MiB): layout unchanged from round 11.
// ---------------------------------------------------------------------------

extern "C" void kernel_launch(void* const* d_in, const int* in_sizes, int n_in,
                              void* d_out, int out_size, void* d_ws, size_t ws_size,
                              hipStream_t stream) {
    const void* tgt = d_in[0];
    const void* mem = d_in[1];
    const void* sWq = d_in[2];  const void* sWk = d_in[3];
    const void* sWv = d_in[4];  const void* sWo = d_in[5];
    const void* cWq = d_in[6];  const void* cWk = d_in[7];
    const void* cWv = d_in[8];  const void* cWo = d_in[9];
    const void* sbq = d_in[10]; const void* sbk = d_in[11];
    const void* sbv = d_in[12]; const void* sbo = d_in[13];
    const void* cbq = d_in[14]; const void* cbk = d_in[15];
    const void* cbv = d_in[16]; const void* cbo = d_in[17];
    const void* fW1 = d_in[18]; const void* fb1 = d_in[19];
    const void* fW2 = d_in[20]; const void* fb2 = d_in[21];
    const void* g1  = d_in[22]; const void* g2  = d_in[23];
    const void* g3  = d_in[24];
    const void* be1 = d_in[25]; const void* be2 = d_in[26];
    const void* be3 = d_in[27];

    char* ws = (char*)d_ws;
    const size_t MB = 1048576;
    ushort_t* qkv = (ushort_t*)(ws + 0 * MB);
    ushort_t* hb  = (ushort_t*)(ws + 0 * MB);    // FFN hidden [4096][2048]
    ushort_t* po  = (ushort_t*)(ws + 12 * MB);
    ushort_t* xb  = (ushort_t*)(ws + 16 * MB);
    ushort_t* tb  = (ushort_t*)(ws + 20 * MB);
    ushort_t* mb  = (ushort_t*)(ws + 24 * MB);
    float*    of  = (float*)   (ws + 20 * MB);   // FFN out f32 [4096][512]
    ushort_t* wb  = (ushort_t*)(ws + 28 * MB);
    float*    pb  = (float*)   (ws + 36 * MB);
    int*   dflag  = (int*)     (ws + 36 * MB + 262144);

    const ushort_t* sWqkv_t = wb + 0;
    const ushort_t* sWo_t   = wb + 786432;
    const ushort_t* cWqkv_t = wb + 1048576;   // cWq_t|cWk_t|cWv_t contiguous
    const ushort_t* cWo_t   = wb + 1835008;
    const ushort_t* fW1_t   = wb + 2097152;
    const ushort_t* fW2_t   = wb + 3145728;

    dim3 blk(256);

    // ---- prep ----
    detect_dtype<<<dim3(1), blk, 0, stream>>>((const ushort_t*)tgt, dflag);
    prep_all<<<dim3(32, 32, 13), blk, 0, stream>>>(
        sWq, sWk, sWv, sWo, cWq, cWk, cWv, cWo, fW1, fW2,
        tgt, mem, sbq, sbk, sbv, sbo, cbq, cbk, cbv, cbo, fb1, fb2,
        wb, tb, mb, pb, dflag);

    dim3 gattn(16, 32);
    dim3 blk512(512);

    // ---- self-attention ----
    gemm_tn<ushort_t, false, 128><<<dim3(32, 12), blk, 0, stream>>>(tb, tb, 0, 512, sWqkv_t, 512, pb + 0, qkv, 1536, 512);
    attn_mfma<<<gattn, blk512, 0, stream>>>(qkv);
    gemm_tn<ushort_t, false, 64><<<dim3(32, 8), blk, 0, stream>>>(qkv, qkv, 0, 1536, sWo_t, 512, pb + 1536, po, 512, 512);
    ln_kernel<true, false, false><<<dim3(4096), blk, 0, stream>>>(tgt, po, g1, be1, xb, dflag);

    // ---- cross-attention (Q-proj and KV-proj fused into one dispatch) ----
    gemm_tn<ushort_t, false, 128><<<dim3(32, 12), blk, 0, stream>>>(xb, mb, 4, 512, cWqkv_t, 512, pb + 2048, qkv, 1536, 512);
    attn_mfma<<<gattn, blk512, 0, stream>>>(qkv);
    gemm_tn<ushort_t, false, 64><<<dim3(32, 8), blk, 0, stream>>>(qkv, qkv, 0, 1536, cWo_t, 512, pb + 3584, po, 512, 512);
    ln_kernel<false, false, false><<<dim3(4096), blk, 0, stream>>>(xb, po, g2, be2, xb, dflag);

    // ---- FFN: full-width, single pass each ----
    gemm_tn<ushort_t, true, 128><<<dim3(32, 16), blk, 0, stream>>>(xb, xb, 0, 512, fW1_t, 512, pb + 4096, hb, 2048, 512);
    gemm_tn<float, false, 64><<<dim3(32, 8), blk, 0, stream>>>(hb, hb, 0, 2048, fW2_t, 2048, pb + 6144, of, 512, 2048);
    ln_kernel<false, true, true><<<dim3(4096), blk, 0, stream>>>(xb, of, g3, be3, d_out, dflag);
}